// Round 4
// baseline (103.554 us; speedup 1.0000x reference)
//
#include <hip/hip_runtime.h>

// out[b,n] = sum_m exp(-||qp[b,n,:2]-sp[b,m,:2]||) * f[b,m] / sum_m exp(-...)
// Shapes: qp [4,4096,3], sp [4,8192,3], feats [4,8192,1], out [4,4096,1] fp32.
//
// R4 model: v_sqrt_f32/v_exp_f32 are ~16 cyc per wave64 inst (trans unit is
// quarter-rate and did NOT widen with SIMD-32) -> hard floor
// 2 trans/pair * 134M pairs => ~27 us. R3 ran ~35 us at only 2 waves/SIMD
// (chain latency exposed). R4: SPLITS 32->64 => 1024 blocks, 4 waves/SIMD,
// QPT=4 keeps the LDS pipe at ~10 us (under the trans floor). Packed fp32
// (v_pk_fma) keeps full-rate VALU at ~4 us. Target: trans-saturated ~28 us.

#define B_DIM   4
#define N_DIM   4096
#define M_DIM   8192
#define NQ      (B_DIM * N_DIM)     // 16384
#define THREADS 256
#define QPT     4                   // queries per thread
#define QPB     (THREADS * QPT)     // 1024 queries per block
#define QGROUPS (NQ / QPB)          // 16
#define SPLITS  64                  // M splits (blockIdx.y)
#define CHUNK   (M_DIM / SPLITS)    // 128 scene points per block

typedef float v2f __attribute__((ext_vector_type(2)));

__global__ __launch_bounds__(THREADS) void mfe_main(
    const float* __restrict__ qp,     // [B,N,3]
    const float* __restrict__ sp,     // [B,M,3]
    const float* __restrict__ feats,  // [B,M,1]
    float* __restrict__ psw,          // [SPLITS][NQ] or [NQ] (atomic)
    float* __restrict__ pswf,         // same
    int use_atomic)
{
    __shared__ float4 pts[CHUNK];          // {x, y, L2*(x^2+y^2), f} : 2 KB

    const float L2 = 2.0813689810056077f;  // (log2 e)^2

    const int tid  = threadIdx.x;
    const int qg   = blockIdx.x;           // 0..QGROUPS-1
    const int s    = blockIdx.y;           // 0..SPLITS-1
    const int lane = tid & 63;
    const int w    = tid >> 6;
    const int qbase = qg * QPB + w * (QPT * 64) + lane;  // +k*64, k=0..3
    const int b     = qg / (N_DIM / QPB);  // batch (uniform per block)

    // Stage this block's 128-point chunk (threads 0..127).
    if (tid < CHUNK) {
        const int m = b * M_DIM + s * CHUNK + tid;
        const float x = sp[m * 3 + 0];
        const float y = sp[m * 3 + 1];
        const float f = feats[m];
        pts[tid] = make_float4(x, y, L2 * fmaf(x, x, y * y), f);
    }

    // Per-query constants: t = L2*d2 = ca*x + cb*y + X2' + Q2'
    float qx[QPT], qy[QPT];
    #pragma unroll
    for (int k = 0; k < QPT; ++k) {
        const int q = qbase + k * 64;
        qx[k] = qp[q * 3 + 0];
        qy[k] = qp[q * 3 + 1];
    }
    const v2f caA = { -2.0f * L2 * qx[0], -2.0f * L2 * qx[1] };
    const v2f caB = { -2.0f * L2 * qx[2], -2.0f * L2 * qx[3] };
    const v2f cbA = { -2.0f * L2 * qy[0], -2.0f * L2 * qy[1] };
    const v2f cbB = { -2.0f * L2 * qy[2], -2.0f * L2 * qy[3] };
    const v2f q2A = { L2 * fmaf(qx[0], qx[0], qy[0] * qy[0]),
                      L2 * fmaf(qx[1], qx[1], qy[1] * qy[1]) };
    const v2f q2B = { L2 * fmaf(qx[2], qx[2], qy[2] * qy[2]),
                      L2 * fmaf(qx[3], qx[3], qy[3] * qy[3]) };

    v2f swA  = {0.f, 0.f}, swB  = {0.f, 0.f};
    v2f swfA = {0.f, 0.f}, swfB = {0.f, 0.f};

    __syncthreads();

    #pragma unroll 4
    for (int j = 0; j < CHUNK; ++j) {
        const float4 P = pts[j];           // wave-uniform addr -> broadcast
        const v2f px = { P.x, P.x };
        const v2f py = { P.y, P.y };
        const v2f pz = { P.z, P.z };
        const v2f pf = { P.w, P.w };

        v2f tA = __builtin_elementwise_fma(caA, px, q2A);
        v2f tB = __builtin_elementwise_fma(caB, px, q2B);
        tA = __builtin_elementwise_fma(cbA, py, tA);
        tB = __builtin_elementwise_fma(cbB, py, tB);
        tA = tA + pz;
        tB = tB + pz;

        v2f wva, wvb;                      // abs folds into sqrt src modifier,
        wva.x = __builtin_amdgcn_exp2f(-__builtin_amdgcn_sqrtf(__builtin_fabsf(tA.x)));
        wva.y = __builtin_amdgcn_exp2f(-__builtin_amdgcn_sqrtf(__builtin_fabsf(tA.y)));
        wvb.x = __builtin_amdgcn_exp2f(-__builtin_amdgcn_sqrtf(__builtin_fabsf(tB.x)));
        wvb.y = __builtin_amdgcn_exp2f(-__builtin_amdgcn_sqrtf(__builtin_fabsf(tB.y)));

        swA += wva;
        swB += wvb;
        swfA = __builtin_elementwise_fma(wva, pf, swfA);
        swfB = __builtin_elementwise_fma(wvb, pf, swfB);
    }

    const float sw_k[QPT]  = { swA.x,  swA.y,  swB.x,  swB.y  };
    const float swf_k[QPT] = { swfA.x, swfA.y, swfB.x, swfB.y };

    if (!use_atomic) {
        #pragma unroll
        for (int k = 0; k < QPT; ++k) {
            const int q = qbase + k * 64;
            psw [s * NQ + q] = sw_k[k];    // coalesced per wave
            pswf[s * NQ + q] = swf_k[k];
        }
    } else {
        #pragma unroll
        for (int k = 0; k < QPT; ++k) {
            const int q = qbase + k * 64;
            atomicAdd(&psw[q],  sw_k[k]);
            atomicAdd(&pswf[q], swf_k[k]);
        }
    }
}

__global__ __launch_bounds__(256) void mfe_div(
    const float* __restrict__ psw,
    const float* __restrict__ pswf,
    float* __restrict__ out, int nsum)
{
    const int i = blockIdx.x * 256 + threadIdx.x;
    float sw = 0.f, swf = 0.f;
    for (int s = 0; s < nsum; ++s) {
        sw  += psw [s * NQ + i];
        swf += pswf[s * NQ + i];
    }
    out[i] = swf / sw;
}

extern "C" void kernel_launch(void* const* d_in, const int* in_sizes, int n_in,
                              void* d_out, int out_size, void* d_ws, size_t ws_size,
                              hipStream_t stream) {
    const float* qp    = (const float*)d_in[0];
    const float* sp    = (const float*)d_in[1];
    const float* feats = (const float*)d_in[2];
    float* out = (float*)d_out;

    const size_t need = (size_t)2 * SPLITS * NQ * sizeof(float);  // 8 MB
    dim3 grid(QGROUPS, SPLITS);

    if (ws_size >= need) {
        float* psw  = (float*)d_ws;
        float* pswf = psw + (size_t)SPLITS * NQ;
        mfe_main<<<grid, THREADS, 0, stream>>>(qp, sp, feats, psw, pswf, 0);
        mfe_div<<<NQ / 256, 256, 0, stream>>>(psw, pswf, out, SPLITS);
    } else {
        float* psw  = (float*)d_ws;       // [NQ]
        float* pswf = psw + NQ;
        hipMemsetAsync(d_ws, 0, 2 * NQ * sizeof(float), stream);
        mfe_main<<<grid, THREADS, 0, stream>>>(qp, sp, feats, psw, pswf, 1);
        mfe_div<<<NQ / 256, 256, 0, stream>>>(psw, pswf, out, 1);
    }
}

// Round 5
// 88.435 us; speedup vs baseline: 1.1710x; 1.1710x over previous
//
#include <hip/hip_runtime.h>

// out[b,n] = sum_m exp(-||qp[b,n,:2]-sp[b,m,:2]||) * f[b,m] / sum_m exp(-...)
// Shapes: qp [4,4096,3], sp [4,8192,3], feats [4,8192,1], out [4,4096,1] fp32.
//
// R5 model: per-pair cost floor = 2 trans insts (v_sqrt_f32, v_exp_f32) at
// ~16 cyc/wave64 -> 134M pairs => ~27 us device-wide. R3/R4 main sat at ~40 us;
// R4's regression was the latency-bound mfe_div (runtime trip count, 64 CUs,
// ~300cyc L2 loads => ~16us). R5: main atomicAdds into a 128KB accumulator
// (fire-and-forget, 64 updates/addr), div becomes 2 loads + 1 divide; point
// loop unrolled 8x for >=16 independent trans chains per wave.

#define B_DIM   4
#define N_DIM   4096
#define M_DIM   8192
#define NQ      (B_DIM * N_DIM)     // 16384
#define THREADS 256
#define QPT     4                   // queries per thread
#define QPB     (THREADS * QPT)     // 1024 queries per block
#define QGROUPS (NQ / QPB)          // 16
#define SPLITS  64                  // M splits (blockIdx.y) -> 1024 blocks
#define CHUNK   (M_DIM / SPLITS)    // 128 scene points per block

typedef float v2f __attribute__((ext_vector_type(2)));

__global__ __launch_bounds__(THREADS) void mfe_main(
    const float* __restrict__ qp,     // [B,N,3]
    const float* __restrict__ sp,     // [B,M,3]
    const float* __restrict__ feats,  // [B,M,1]
    float* __restrict__ psw,          // [NQ] zeroed accumulator
    float* __restrict__ pswf)         // [NQ] zeroed accumulator
{
    __shared__ float4 pts[CHUNK];          // {x, y, L2*(x^2+y^2), f} : 2 KB

    const float L2 = 2.0813689810056077f;  // (log2 e)^2

    const int tid  = threadIdx.x;
    const int qg   = blockIdx.x;           // 0..QGROUPS-1
    const int s    = blockIdx.y;           // 0..SPLITS-1
    const int lane = tid & 63;
    const int w    = tid >> 6;
    const int qbase = qg * QPB + w * (QPT * 64) + lane;  // +k*64, k=0..3
    const int b     = qg / (N_DIM / QPB);  // batch (uniform per block)

    // Stage this block's 128-point chunk (threads 0..127).
    if (tid < CHUNK) {
        const int m = b * M_DIM + s * CHUNK + tid;
        const float x = sp[m * 3 + 0];
        const float y = sp[m * 3 + 1];
        const float f = feats[m];
        pts[tid] = make_float4(x, y, L2 * fmaf(x, x, y * y), f);
    }

    // Per-query constants: t = L2*d2 = ca*x + cb*y + X2' + Q2'
    float qx[QPT], qy[QPT];
    #pragma unroll
    for (int k = 0; k < QPT; ++k) {
        const int q = qbase + k * 64;
        qx[k] = qp[q * 3 + 0];
        qy[k] = qp[q * 3 + 1];
    }
    const v2f caA = { -2.0f * L2 * qx[0], -2.0f * L2 * qx[1] };
    const v2f caB = { -2.0f * L2 * qx[2], -2.0f * L2 * qx[3] };
    const v2f cbA = { -2.0f * L2 * qy[0], -2.0f * L2 * qy[1] };
    const v2f cbB = { -2.0f * L2 * qy[2], -2.0f * L2 * qy[3] };
    const v2f q2A = { L2 * fmaf(qx[0], qx[0], qy[0] * qy[0]),
                      L2 * fmaf(qx[1], qx[1], qy[1] * qy[1]) };
    const v2f q2B = { L2 * fmaf(qx[2], qx[2], qy[2] * qy[2]),
                      L2 * fmaf(qx[3], qx[3], qy[3] * qy[3]) };

    v2f swA  = {0.f, 0.f}, swB  = {0.f, 0.f};
    v2f swfA = {0.f, 0.f}, swfB = {0.f, 0.f};

    __syncthreads();

    #pragma unroll 8
    for (int j = 0; j < CHUNK; ++j) {
        const float4 P = pts[j];           // wave-uniform addr -> broadcast
        const v2f px = { P.x, P.x };
        const v2f py = { P.y, P.y };
        const v2f pz = { P.z, P.z };
        const v2f pf = { P.w, P.w };

        v2f tA = __builtin_elementwise_fma(caA, px, q2A);
        v2f tB = __builtin_elementwise_fma(caB, px, q2B);
        tA = __builtin_elementwise_fma(cbA, py, tA);
        tB = __builtin_elementwise_fma(cbB, py, tB);
        tA = tA + pz;
        tB = tB + pz;

        v2f wva, wvb;                      // abs/neg fold into src modifiers
        wva.x = __builtin_amdgcn_exp2f(-__builtin_amdgcn_sqrtf(__builtin_fabsf(tA.x)));
        wva.y = __builtin_amdgcn_exp2f(-__builtin_amdgcn_sqrtf(__builtin_fabsf(tA.y)));
        wvb.x = __builtin_amdgcn_exp2f(-__builtin_amdgcn_sqrtf(__builtin_fabsf(tB.x)));
        wvb.y = __builtin_amdgcn_exp2f(-__builtin_amdgcn_sqrtf(__builtin_fabsf(tB.y)));

        swA += wva;
        swB += wvb;
        swfA = __builtin_elementwise_fma(wva, pf, swfA);
        swfB = __builtin_elementwise_fma(wvb, pf, swfB);
    }

    const float sw_k[QPT]  = { swA.x,  swA.y,  swB.x,  swB.y  };
    const float swf_k[QPT] = { swfA.x, swfA.y, swfB.x, swfB.y };

    #pragma unroll
    for (int k = 0; k < QPT; ++k) {
        const int q = qbase + k * 64;
        atomicAdd(&psw[q],  sw_k[k]);      // fire-and-forget, device-scope
        atomicAdd(&pswf[q], swf_k[k]);
    }
}

__global__ __launch_bounds__(256) void mfe_div(
    const float* __restrict__ psw,
    const float* __restrict__ pswf,
    float* __restrict__ out)
{
    const int i = blockIdx.x * 256 + threadIdx.x;
    out[i] = pswf[i] / psw[i];
}

extern "C" void kernel_launch(void* const* d_in, const int* in_sizes, int n_in,
                              void* d_out, int out_size, void* d_ws, size_t ws_size,
                              hipStream_t stream) {
    const float* qp    = (const float*)d_in[0];
    const float* sp    = (const float*)d_in[1];
    const float* feats = (const float*)d_in[2];
    float* out = (float*)d_out;

    float* psw  = (float*)d_ws;            // [NQ]
    float* pswf = psw + NQ;                // [NQ]

    // ws is re-poisoned to 0xAA before every call — zero the accumulators.
    hipMemsetAsync(d_ws, 0, 2 * NQ * sizeof(float), stream);

    dim3 grid(QGROUPS, SPLITS);
    mfe_main<<<grid, THREADS, 0, stream>>>(qp, sp, feats, psw, pswf);
    mfe_div<<<NQ / 256, 256, 0, stream>>>(psw, pswf, out);
}

// Round 9
// 87.810 us; speedup vs baseline: 1.1793x; 1.0071x over previous
//
#include <hip/hip_runtime.h>

// out[b,n] = sum_m exp(-||qp[b,n,:2]-sp[b,m,:2]||) * f[b,m] / sum_m exp(-...)
// Shapes: qp [4,4096,3], sp [4,8192,3], feats [4,8192,1], out [4,4096,1] fp32.
//
// R9: R7/R8 proved hand-written VOP3P inline asm is unverifiable here (op_sel
// / default-modifier semantics bit us twice). This round: R8's layout —
// 2 POINTS per v2f lane pair (LDS float4 {x0,x1,y0,y1}/{z0,z1,f0,f1}),
// query constants splatted to v2f ONCE outside the loop — with all math as
// __builtin_elementwise_fma / vector add, so the inner loop is pure
// element-wise v2f with no in-loop splats: correct by construction, and the
// best-case IR shape for LLVM to select v_pk_fma_f32/v_pk_add_f32 itself.
// Model: trans floor 27.3us (v_sqrt+v_exp ~16cyc/wave64 each, 134M pairs);
// packed VALU ~4.3us, LDS ~10us/CU -> main ~33us packed / ~37 scalarized.

#define B_DIM   4
#define N_DIM   4096
#define M_DIM   8192
#define NQ      (B_DIM * N_DIM)     // 16384
#define THREADS 256
#define QPT     4                   // queries per thread
#define QPB     (THREADS * QPT)     // 1024 queries per block
#define QGROUPS (NQ / QPB)          // 16
#define SPLITS  64                  // M splits (blockIdx.y) -> 1024 blocks
#define CHUNK   (M_DIM / SPLITS)    // 128 scene points per block
#define PAIRS   (CHUNK / 2)         // 64 point-pairs

typedef float v2f __attribute__((ext_vector_type(2)));

__global__ __launch_bounds__(THREADS) void mfe_main(
    const float* __restrict__ qp,     // [B,N,3]
    const float* __restrict__ sp,     // [B,M,3]
    const float* __restrict__ feats,  // [B,M,1]
    float* __restrict__ psw,          // [NQ] zeroed accumulator
    float* __restrict__ pswf)         // [NQ] zeroed accumulator
{
    __shared__ float4 xy2[PAIRS];          // {x0, x1, y0, y1} : 1 KB
    __shared__ float4 zf2[PAIRS];          // {z0, z1, f0, f1} : 1 KB

    const float L2 = 2.0813689810056077f;  // (log2 e)^2

    const int tid  = threadIdx.x;
    const int qg   = blockIdx.x;           // 0..QGROUPS-1
    const int s    = blockIdx.y;           // 0..SPLITS-1
    const int lane = tid & 63;
    const int w    = tid >> 6;
    const int qbase = qg * QPB + w * (QPT * 64) + lane;  // +k*64, k=0..3
    const int b     = qg / (N_DIM / QPB);  // batch (uniform per block)

    // Stage: threads 0..63 each build one point-pair.
    if (tid < PAIRS) {
        const int m0 = b * M_DIM + s * CHUNK + 2 * tid;
        const float x0 = sp[m0 * 3 + 0], y0 = sp[m0 * 3 + 1];
        const float x1 = sp[m0 * 3 + 3], y1 = sp[m0 * 3 + 4];
        const float f0 = feats[m0], f1 = feats[m0 + 1];
        xy2[tid] = make_float4(x0, x1, y0, y1);
        zf2[tid] = make_float4(L2 * fmaf(x0, x0, y0 * y0),
                               L2 * fmaf(x1, x1, y1 * y1), f0, f1);
    }

    // Per-query constants, splatted into pairs ONCE (movs outside the loop).
    // t = L2*d2 = ca*x + cb*y + (z + q2)
    v2f caS[QPT], cbS[QPT], q2S[QPT];
    #pragma unroll
    for (int k = 0; k < QPT; ++k) {
        const int q = qbase + k * 64;
        const float qx = qp[q * 3 + 0];
        const float qy = qp[q * 3 + 1];
        const float ca = -2.0f * L2 * qx;
        const float cb = -2.0f * L2 * qy;
        const float q2 = L2 * fmaf(qx, qx, qy * qy);
        caS[k] = (v2f){ ca, ca };
        cbS[k] = (v2f){ cb, cb };
        q2S[k] = (v2f){ q2, q2 };
    }

    v2f sw[QPT], swf[QPT];
    #pragma unroll
    for (int k = 0; k < QPT; ++k) { sw[k] = (v2f){0.f, 0.f}; swf[k] = (v2f){0.f, 0.f}; }

    __syncthreads();

    #pragma unroll 8
    for (int j = 0; j < PAIRS; ++j) {
        const float4 XY = xy2[j];          // wave-uniform addr -> broadcast
        const float4 ZF = zf2[j];
        const v2f X = { XY.x, XY.y };      // adjacent regs straight from b128
        const v2f Y = { XY.z, XY.w };
        const v2f Z = { ZF.x, ZF.y };
        const v2f F = { ZF.z, ZF.w };

        #pragma unroll
        for (int k = 0; k < QPT; ++k) {
            // t = ca*X + cb*Y + (Z + q2) — pure element-wise v2f
            const v2f t = __builtin_elementwise_fma(
                caS[k], X, __builtin_elementwise_fma(cbS[k], Y, Z + q2S[k]));
            v2f wv;                        // abs/neg fold into src modifiers
            wv.x = __builtin_amdgcn_exp2f(-__builtin_amdgcn_sqrtf(__builtin_fabsf(t.x)));
            wv.y = __builtin_amdgcn_exp2f(-__builtin_amdgcn_sqrtf(__builtin_fabsf(t.y)));
            sw[k]  = sw[k] + wv;
            swf[k] = __builtin_elementwise_fma(wv, F, swf[k]);
        }
    }

    #pragma unroll
    for (int k = 0; k < QPT; ++k) {
        const int q = qbase + k * 64;
        atomicAdd(&psw[q],  sw[k].x  + sw[k].y);   // fire-and-forget
        atomicAdd(&pswf[q], swf[k].x + swf[k].y);
    }
}

__global__ __launch_bounds__(256) void mfe_div(
    const float* __restrict__ psw,
    const float* __restrict__ pswf,
    float* __restrict__ out)
{
    const int i = blockIdx.x * 256 + threadIdx.x;
    out[i] = pswf[i] / psw[i];
}

extern "C" void kernel_launch(void* const* d_in, const int* in_sizes, int n_in,
                              void* d_out, int out_size, void* d_ws, size_t ws_size,
                              hipStream_t stream) {
    const float* qp    = (const float*)d_in[0];
    const float* sp    = (const float*)d_in[1];
    const float* feats = (const float*)d_in[2];
    float* out = (float*)d_out;

    float* psw  = (float*)d_ws;            // [NQ]
    float* pswf = psw + NQ;                // [NQ]

    // ws is re-poisoned to 0xAA before every call — zero the accumulators.
    hipMemsetAsync(d_ws, 0, 2 * NQ * sizeof(float), stream);

    dim3 grid(QGROUPS, SPLITS);
    mfe_main<<<grid, THREADS, 0, stream>>>(qp, sp, feats, psw, pswf);
    mfe_div<<<NQ / 256, 256, 0, stream>>>(psw, pswf, out);
}